// Round 6
// baseline (167.479 us; speedup 1.0000x reference)
//
#include <hip/hip_runtime.h>
#include <math.h>

namespace {

constexpr int   kB     = 16;
constexpr int   kA     = 65536;
constexpr int   kM     = 32;
constexpr int   kC     = 20;
constexpr float kImg   = 600.0f;
constexpr int   kBlock = 256;
constexpr int   kGridX = kA / kBlock;           // 256
constexpr int   kNBlocks = kGridX * kB;         // 4096

__device__ __forceinline__ float smooth_l1(float d) {
    float ad = fabsf(d);
    return ad < 1.0f ? 0.5f * d * d : ad - 0.5f;
}

// Background-class focal contribution: 0.75 * sigmoid(x)^2 * softplus(x).
// Used identically in the dense sweep and the sparse correction so the
// subtraction cancels almost exactly.
__device__ __forceinline__ float bg_contrib(float x) {
    float e  = __expf(-fabsf(x));                 // exp(-|x|)
    float u  = 1.0f + e;
    float r  = __builtin_amdgcn_rcpf(u);
    float lg = __logf(u);                         // log(1+e)
    float p  = (x >= 0.0f) ? r : e * r;           // sigmoid(x)
    float sp = lg + fmaxf(x, 0.0f);               // softplus(x)
    return 0.75f * p * p * sp;
}

// Target-class focal contribution: 0.25 * (1-sigmoid(x))^2 * softplus(-x).
__device__ __forceinline__ float tgt_contrib(float x) {
    float e  = __expf(-fabsf(x));
    float u  = 1.0f + e;
    float r  = __builtin_amdgcn_rcpf(u);
    float lg = __logf(u);
    float q  = (x >= 0.0f) ? e * r : r;           // sigmoid(-x) = 1-p
    float sp = lg + fmaxf(-x, 0.0f);              // softplus(-x)
    return 0.25f * q * q * sp;
}

__global__ __launch_bounds__(kBlock) void retina_main(
    const float* __restrict__ loc_preds,   // [B, A, 4]
    const float* __restrict__ cls_preds,   // [B, A, C]
    const float* __restrict__ iou_boxes,   // [A, 4] xywh
    const float* __restrict__ targets,     // [B*M, 6]
    float* __restrict__ partial)           // [kNBlocks][3]
{
    __shared__ float4 sbox[kM];    // x1, y1, x2+1, y2+1 (pixels)
    __shared__ float4 sxywh[kM];   // cx, cy, w, h (pixels)
    __shared__ float  sarea[kM];   // target area (+1 convention)
    __shared__ int    slab[kM];
    __shared__ float  sred[3][kBlock / 64];

    const int b  = blockIdx.y;
    const int ab = blockIdx.x * kBlock;
    const int a  = ab + threadIdx.x;

    if (threadIdx.x < kM) {
        const float* t = targets + ((size_t)(b * kM + threadIdx.x)) * 6;
        float cx = t[2] * kImg, cy = t[3] * kImg;
        float w  = t[4] * kImg, h  = t[5] * kImg;
        float x1  = cx - w * 0.5f,        y1  = cy - h * 0.5f;
        float x2p = cx + w * 0.5f + 1.0f, y2p = cy + h * 0.5f + 1.0f;
        sbox[threadIdx.x]  = make_float4(x1, y1, x2p, y2p);
        sxywh[threadIdx.x] = make_float4(cx, cy, w, h);
        sarea[threadIdx.x] = (x2p - x1) * (y2p - y1);
        slab[threadIdx.x]  = (int)t[1];
    }

    // Short-lived global loads for phase 1.
    const float4 an = *(const float4*)(iou_boxes + (size_t)a * 4);
    const float4 lp = *(const float4*)(loc_preds + ((size_t)b * kA + a) * 4);

    __syncthreads();

    // ---- Phase 1: IoU argmax for this thread's anchor ----
    const float ax1  = an.x - an.z * 0.5f;
    const float ay1  = an.y - an.w * 0.5f;
    const float ax2p = an.x + an.z * 0.5f + 1.0f;
    const float ay2p = an.y + an.w * 0.5f + 1.0f;
    const float aarea = (ax2p - ax1) * (ay2p - ay1);

    float best = -1.0f;
    int   mid  = 0;
#pragma unroll
    for (int m = 0; m < kM; ++m) {
        float4 q = sbox[m];
        float lx = fmaxf(ax1,  q.x);
        float ly = fmaxf(ay1,  q.y);
        float rx = fminf(ax2p, q.z);
        float ry = fminf(ay2p, q.w);
        float w  = fmaxf(rx - lx, 0.0f);
        float h  = fmaxf(ry - ly, 0.0f);
        float inter = w * h;
        float uni   = aarea + sarea[m] - inter;
        float iou   = inter * __builtin_amdgcn_rcpf(uni);
        if (iou > best) { best = iou; mid = m; }
    }

    const bool pos = best >= 0.5f;
    const bool ign = (best > 0.4f) && !pos;

    float loc_sum = 0.0f, npos = 0.0f;
    if (pos) {
        npos = 1.0f;
        float4 mb = sxywh[mid];
        float ltx = (mb.x - an.x) * __builtin_amdgcn_rcpf(an.z);
        float lty = (mb.y - an.y) * __builtin_amdgcn_rcpf(an.w);
        float ltw = __logf(mb.z * __builtin_amdgcn_rcpf(an.z));
        float lth = __logf(mb.w * __builtin_amdgcn_rcpf(an.w));
        loc_sum = smooth_l1(lp.x - ltx) + smooth_l1(lp.y - lty) +
                  smooth_l1(lp.z - ltw) + smooth_l1(lp.w - lth);
    }

    // ---- Phase 2: dense focal sweep, ALL elements as background ----
    // No scode, no index math, no selects on target: 3 trans + ~11 VALU/elem.
    const float* cp0 = cls_preds + ((size_t)b * kA + ab) * kC;
    float cls_sum = 0.0f;
#pragma unroll
    for (int i = 0; i < kC / 4; ++i) {
        const float4 v = *(const float4*)(cp0 + ((size_t)i * kBlock + threadIdx.x) * 4);
        cls_sum += bg_contrib(v.x) + bg_contrib(v.y) +
                   bg_contrib(v.z) + bg_contrib(v.w);
    }

    // ---- Phase 3: sparse correction for this thread's own anchor ----
    // Rare (few % of anchors): re-read own row (L1/L2-hot from phase 2).
    if (pos | ign) {
        const float* own = cls_preds + ((size_t)b * kA + a) * kC;
        if (pos) {
            const int c = slab[mid];           // target class 0..19
            float x = own[c];
            cls_sum += tgt_contrib(x) - bg_contrib(x);
        } else {
            float s = 0.0f;
#pragma unroll
            for (int i = 0; i < kC / 4; ++i) {
                float4 v = *(const float4*)(own + i * 4);
                s += bg_contrib(v.x) + bg_contrib(v.y) +
                     bg_contrib(v.z) + bg_contrib(v.w);
            }
            cls_sum -= s;
        }
    }

    // ---- Reduce: wave shuffle -> LDS -> per-block partial ----
#pragma unroll
    for (int off = 32; off > 0; off >>= 1) {
        loc_sum += __shfl_down(loc_sum, off);
        cls_sum += __shfl_down(cls_sum, off);
        npos    += __shfl_down(npos, off);
    }
    const int lane = threadIdx.x & 63;
    const int wid  = threadIdx.x >> 6;
    if (lane == 0) {
        sred[0][wid] = loc_sum;
        sred[1][wid] = cls_sum;
        sred[2][wid] = npos;
    }
    __syncthreads();
    if (threadIdx.x == 0) {
        float l = 0.0f, c = 0.0f, n = 0.0f;
#pragma unroll
        for (int i = 0; i < kBlock / 64; ++i) {
            l += sred[0][i]; c += sred[1][i]; n += sred[2][i];
        }
        const int bid = blockIdx.y * gridDim.x + blockIdx.x;
        partial[3 * bid + 0] = l;
        partial[3 * bid + 1] = c;
        partial[3 * bid + 2] = n;
    }
}

__global__ __launch_bounds__(1024) void retina_final(
    const float* __restrict__ partial, float* __restrict__ out)
{
    __shared__ float s[3][16];
    float l = 0.0f, c = 0.0f, n = 0.0f;
    for (int i = threadIdx.x; i < kNBlocks; i += 1024) {
        l += partial[3 * i + 0];
        c += partial[3 * i + 1];
        n += partial[3 * i + 2];
    }
#pragma unroll
    for (int off = 32; off > 0; off >>= 1) {
        l += __shfl_down(l, off);
        c += __shfl_down(c, off);
        n += __shfl_down(n, off);
    }
    const int lane = threadIdx.x & 63;
    const int wid  = threadIdx.x >> 6;
    if (lane == 0) { s[0][wid] = l; s[1][wid] = c; s[2][wid] = n; }
    __syncthreads();
    if (threadIdx.x == 0) {
        float L = 0.0f, C = 0.0f, N = 0.0f;
#pragma unroll
        for (int i = 0; i < 16; ++i) { L += s[0][i]; C += s[1][i]; N += s[2][i]; }
        float np  = fmaxf(1.0f, N);
        float inv = 1.0f / np;
        out[0] = (L + C) * inv;
        out[1] = L * inv;
        out[2] = C * inv;
    }
}

}  // namespace

extern "C" void kernel_launch(void* const* d_in, const int* in_sizes, int n_in,
                              void* d_out, int out_size, void* d_ws, size_t ws_size,
                              hipStream_t stream) {
    const float* loc_preds = (const float*)d_in[0];
    const float* cls_preds = (const float*)d_in[1];
    const float* iou_boxes = (const float*)d_in[2];
    const float* targets   = (const float*)d_in[3];
    float* out     = (float*)d_out;
    float* partial = (float*)d_ws;   // 4096*3 floats, fully overwritten each call

    dim3 grid(kGridX, kB);
    retina_main<<<grid, kBlock, 0, stream>>>(loc_preds, cls_preds, iou_boxes, targets, partial);
    retina_final<<<1, 1024, 0, stream>>>(partial, out);
}

// Round 7
// 157.030 us; speedup vs baseline: 1.0665x; 1.0665x over previous
//
#include <hip/hip_runtime.h>
#include <math.h>

namespace {

constexpr int   kB     = 16;
constexpr int   kA     = 65536;
constexpr int   kM     = 32;
constexpr int   kC     = 20;
constexpr float kImg   = 600.0f;
constexpr int   kBlock = 256;
constexpr int   kGridX = kA / kBlock;           // 256
constexpr int   kNBlocks = kGridX * kB;         // 4096

// d_ws layout: sA[512] float4 | sB[512] float4 | sC[512] float2 | partial[4096*3]
constexpr size_t kOffB = (size_t)kB * kM;       // in float4 units
constexpr size_t kOffC = 2 * kOffB;             // float4 units boundary

__device__ __forceinline__ float smooth_l1(float d) {
    float ad = fabsf(d);
    return ad < 1.0f ? 0.5f * d * d : ad - 0.5f;
}

__device__ __forceinline__ float bg_contrib(float x) {
    float e  = __expf(-fabsf(x));                 // exp(-|x|)
    float u  = 1.0f + e;
    float r  = __builtin_amdgcn_rcpf(u);
    float lg = __logf(u);                         // log(1+e)
    float p  = (x >= 0.0f) ? r : e * r;           // sigmoid(x)
    float sp = lg + fmaxf(x, 0.0f);               // softplus(x)
    return 0.75f * p * p * sp;
}

__device__ __forceinline__ float tgt_contrib(float x) {
    float e  = __expf(-fabsf(x));
    float u  = 1.0f + e;
    float r  = __builtin_amdgcn_rcpf(u);
    float lg = __logf(u);
    float q  = (x >= 0.0f) ? e * r : r;           // 1 - sigmoid(x)
    float sp = lg + fmaxf(-x, 0.0f);              // softplus(-x)
    return 0.25f * q * q * sp;
}

// ---- Prep: targets -> per-image box tables (consumed via scalar loads) ----
__global__ __launch_bounds__(512) void prep_kernel(
    const float* __restrict__ targets,
    float4* __restrict__ sA,    // x1, y1, x2+1, y2+1
    float4* __restrict__ sB,    // cx, cy, w, h
    float2* __restrict__ sC)    // area, label
{
    const int i = threadIdx.x;           // 512 = kB*kM entries
    const float* t = targets + (size_t)i * 6;
    float cx = t[2] * kImg, cy = t[3] * kImg;
    float w  = t[4] * kImg, h  = t[5] * kImg;
    float x1  = cx - w * 0.5f,        y1  = cy - h * 0.5f;
    float x2p = cx + w * 0.5f + 1.0f, y2p = cy + h * 0.5f + 1.0f;
    sA[i] = make_float4(x1, y1, x2p, y2p);
    sB[i] = make_float4(cx, cy, w, h);
    sC[i] = make_float2((x2p - x1) * (y2p - y1), t[1]);
}

__global__ __launch_bounds__(kBlock) void retina_main(
    const float* __restrict__ loc_preds,   // [B, A, 4]
    const float* __restrict__ cls_preds,   // [B, A, C]
    const float* __restrict__ iou_boxes,   // [A, 4] xywh
    const float4* __restrict__ sA,         // [B*M]
    const float4* __restrict__ sB,         // [B*M]
    const float2* __restrict__ sC,         // [B*M]
    float* __restrict__ partial)           // [kNBlocks][3]
{
    __shared__ float sred[3][kBlock / 64];

    const int b  = blockIdx.y;
    const int ab = blockIdx.x * kBlock;
    const int a  = ab + threadIdx.x;

    // ---- Issue ALL global vector loads up front; latency hides behind IoU ----
    const float4 an = *(const float4*)(iou_boxes + (size_t)a * 4);
    const float4 lp = *(const float4*)(loc_preds + ((size_t)b * kA + a) * 4);
    const float* cp0 = cls_preds + ((size_t)b * kA + ab) * kC;
    float4 cv[kC / 4];
#pragma unroll
    for (int i = 0; i < kC / 4; ++i)
        cv[i] = *(const float4*)(cp0 + ((size_t)i * kBlock + threadIdx.x) * 4);

    // Wave-uniform box tables (scalar loads -> SGPRs, no LDS, no barrier).
    const float4* bA = sA + (size_t)b * kM;
    const float2* bC = sC + (size_t)b * kM;

    // ---- Phase 1: IoU argmax, two independent chains (halved serial depth) ----
    const float ax1  = an.x - an.z * 0.5f;
    const float ay1  = an.y - an.w * 0.5f;
    const float ax2p = an.x + an.z * 0.5f + 1.0f;
    const float ay2p = an.y + an.w * 0.5f + 1.0f;
    const float aarea = (ax2p - ax1) * (ay2p - ay1);

    float best0 = -1.0f, best1 = -1.0f;
    int   mid0  = 0,     mid1  = kM / 2;
#pragma unroll
    for (int m = 0; m < kM / 2; ++m) {
        {
            const float4 q  = bA[m];
            const float  ta = bC[m].x;
            float w  = fmaxf(fminf(ax2p, q.z) - fmaxf(ax1, q.x), 0.0f);
            float h  = fmaxf(fminf(ay2p, q.w) - fmaxf(ay1, q.y), 0.0f);
            float inter = w * h;
            float iou = inter * __builtin_amdgcn_rcpf(aarea + ta - inter);
            if (iou > best0) { best0 = iou; mid0 = m; }
        }
        {
            const int mm = m + kM / 2;
            const float4 q  = bA[mm];
            const float  ta = bC[mm].x;
            float w  = fmaxf(fminf(ax2p, q.z) - fmaxf(ax1, q.x), 0.0f);
            float h  = fmaxf(fminf(ay2p, q.w) - fmaxf(ay1, q.y), 0.0f);
            float inter = w * h;
            float iou = inter * __builtin_amdgcn_rcpf(aarea + ta - inter);
            if (iou > best1) { best1 = iou; mid1 = mm; }
        }
    }
    // Merge (ties -> lower index = chain 0, matching first-max argmax).
    const float best = (best1 > best0) ? best1 : best0;
    const int   mid  = (best1 > best0) ? mid1  : mid0;

    const bool pos = best >= 0.5f;
    const bool ign = (best > 0.4f) && !pos;

    float loc_sum = 0.0f, npos = 0.0f;
    if (pos) {
        npos = 1.0f;
        float4 mb = sB[(size_t)b * kM + mid];   // rare per-lane gather, L2-hot
        float ltx = (mb.x - an.x) * __builtin_amdgcn_rcpf(an.z);
        float lty = (mb.y - an.y) * __builtin_amdgcn_rcpf(an.w);
        float ltw = __logf(mb.z * __builtin_amdgcn_rcpf(an.z));
        float lth = __logf(mb.w * __builtin_amdgcn_rcpf(an.w));
        loc_sum = smooth_l1(lp.x - ltx) + smooth_l1(lp.y - lty) +
                  smooth_l1(lp.z - ltw) + smooth_l1(lp.w - lth);
    }

    // ---- Phase 2: dense focal sweep on prefetched cv ----
    float cls_sum = 0.0f;
#pragma unroll
    for (int i = 0; i < kC / 4; ++i) {
        cls_sum += bg_contrib(cv[i].x) + bg_contrib(cv[i].y) +
                   bg_contrib(cv[i].z) + bg_contrib(cv[i].w);
    }

    // ---- Phase 3: sparse correction (rare) ----
    if (pos | ign) {
        const float* own = cls_preds + ((size_t)b * kA + a) * kC;
        if (pos) {
            const int c = (int)sC[(size_t)b * kM + mid].y;  // label 0..19
            float x = own[c];
            cls_sum += tgt_contrib(x) - bg_contrib(x);
        } else {
            float s = 0.0f;
#pragma unroll
            for (int i = 0; i < kC / 4; ++i) {
                float4 v = *(const float4*)(own + i * 4);
                s += bg_contrib(v.x) + bg_contrib(v.y) +
                     bg_contrib(v.z) + bg_contrib(v.w);
            }
            cls_sum -= s;
        }
    }

    // ---- Reduce: wave shuffle -> LDS -> per-block partial ----
#pragma unroll
    for (int off = 32; off > 0; off >>= 1) {
        loc_sum += __shfl_down(loc_sum, off);
        cls_sum += __shfl_down(cls_sum, off);
        npos    += __shfl_down(npos, off);
    }
    const int lane = threadIdx.x & 63;
    const int wid  = threadIdx.x >> 6;
    if (lane == 0) {
        sred[0][wid] = loc_sum;
        sred[1][wid] = cls_sum;
        sred[2][wid] = npos;
    }
    __syncthreads();
    if (threadIdx.x == 0) {
        float l = 0.0f, c = 0.0f, n = 0.0f;
#pragma unroll
        for (int i = 0; i < kBlock / 64; ++i) {
            l += sred[0][i]; c += sred[1][i]; n += sred[2][i];
        }
        const int bid = blockIdx.y * gridDim.x + blockIdx.x;
        partial[3 * bid + 0] = l;
        partial[3 * bid + 1] = c;
        partial[3 * bid + 2] = n;
    }
}

__global__ __launch_bounds__(1024) void retina_final(
    const float* __restrict__ partial, float* __restrict__ out)
{
    __shared__ float s[3][16];
    float l = 0.0f, c = 0.0f, n = 0.0f;
    for (int i = threadIdx.x; i < kNBlocks; i += 1024) {
        l += partial[3 * i + 0];
        c += partial[3 * i + 1];
        n += partial[3 * i + 2];
    }
#pragma unroll
    for (int off = 32; off > 0; off >>= 1) {
        l += __shfl_down(l, off);
        c += __shfl_down(c, off);
        n += __shfl_down(n, off);
    }
    const int lane = threadIdx.x & 63;
    const int wid  = threadIdx.x >> 6;
    if (lane == 0) { s[0][wid] = l; s[1][wid] = c; s[2][wid] = n; }
    __syncthreads();
    if (threadIdx.x == 0) {
        float L = 0.0f, C = 0.0f, N = 0.0f;
#pragma unroll
        for (int i = 0; i < 16; ++i) { L += s[0][i]; C += s[1][i]; N += s[2][i]; }
        float np  = fmaxf(1.0f, N);
        float inv = 1.0f / np;
        out[0] = (L + C) * inv;
        out[1] = L * inv;
        out[2] = C * inv;
    }
}

}  // namespace

extern "C" void kernel_launch(void* const* d_in, const int* in_sizes, int n_in,
                              void* d_out, int out_size, void* d_ws, size_t ws_size,
                              hipStream_t stream) {
    const float* loc_preds = (const float*)d_in[0];
    const float* cls_preds = (const float*)d_in[1];
    const float* iou_boxes = (const float*)d_in[2];
    const float* targets   = (const float*)d_in[3];
    float* out = (float*)d_out;

    float4* sA = (float4*)d_ws;
    float4* sB = sA + kOffB;
    float2* sC = (float2*)(sA + kOffC);
    float* partial = (float*)(sC + (size_t)kB * kM);

    prep_kernel<<<1, 512, 0, stream>>>(targets, sA, sB, sC);
    dim3 grid(kGridX, kB);
    retina_main<<<grid, kBlock, 0, stream>>>(loc_preds, cls_preds, iou_boxes,
                                             sA, sB, sC, partial);
    retina_final<<<1, 1024, 0, stream>>>(partial, out);
}